// Round 2
// baseline (1701.719 us; speedup 1.0000x reference)
//
#include <hip/hip_runtime.h>

#define L_NUM 2
#define H_NUM 8
#define D_DIM 64
#define HID_D 512
#define FF_D  2048
#define S_SEQ 256
#define B_NUM 8

// ---------------------------------------------------------------------------
// Per-head softmax: h (S,B,HID) f32 -> xs (B,H,S,D) f32. One wave per 64-row.
// ---------------------------------------------------------------------------
__global__ __launch_bounds__(256) void softmax_xs_k(
    const float* __restrict__ h, float* __restrict__ xs)
{
  int rid  = blockIdx.x*4 + (threadIdx.x>>6);   // (s*B+b)*H + hd
  int lane = threadIdx.x & 63;
  int hd = rid & (H_NUM-1);
  int sb = rid >> 3;                            // s*B + b
  int b  = sb & (B_NUM-1);
  int s  = sb >> 3;
  float v = h[(size_t)sb*HID_D + hd*D_DIM + lane];
  float m = v;
  #pragma unroll
  for (int off=32; off; off>>=1) m = fmaxf(m, __shfl_xor(m, off));
  float e = __expf(v-m);
  float sum = e;
  #pragma unroll
  for (int off=32; off; off>>=1) sum += __shfl_xor(sum, off);
  xs[(((size_t)(b*H_NUM+hd))*S_SEQ + s)*D_DIM + lane] = e/sum;
}

// ---------------------------------------------------------------------------
// SRWM sequential scan. 1 block per (b,h). 4 waves:
//  wave0: Wy (rows in regs), wave1: Wq, wave2: Wk, wave3: wb (D x 4).
// ---------------------------------------------------------------------------
__global__ __launch_bounds__(256) void scan_k(
    const float* __restrict__ xs,                 // (B,H,S,D) f32
    const float* __restrict__ st_y, const float* __restrict__ st_q,
    const float* __restrict__ st_k, const float* __restrict__ st_b, // layer slices
    const float* __restrict__ p_y,  const float* __restrict__ p_q,
    const float* __restrict__ p_k,  const float* __restrict__ p_b,  // (H,D,D)/(H,D,4)
    float* __restrict__ y_out,                    // (S,B,HID) f32
    float* __restrict__ o_sy, float* __restrict__ o_sq,
    float* __restrict__ o_sk, float* __restrict__ o_sb)
{
  const int bh = blockIdx.x;
  const int b  = bh >> 3, hh = bh & 7;
  const int wave = threadIdx.x >> 6, lane = threadIdx.x & 63;

  __shared__ __align__(16) float q_s[64];
  __shared__ __align__(16) float k_s[64];
  __shared__ float beta_s[4];

  float W[64];                                   // wave<3: row `lane` of its matrix
  float wb0=0.f, wb1=0.f, wb2=0.f, wb3=0.f;      // wave3: row `lane` of wb

  if (wave < 3) {
    const float* st = (wave==0)? st_y : (wave==1)? st_q : st_k;
    const float* pp = (wave==0)? p_y  : (wave==1)? p_q  : p_k;
    const float4* s4 = reinterpret_cast<const float4*>(st + ((size_t)bh*64 + lane)*64);
    const float4* p4 = reinterpret_cast<const float4*>(pp + ((size_t)hh*64 + lane)*64);
    #pragma unroll
    for (int c=0;c<16;c++){
      float4 a = s4[c], p = p4[c];
      W[c*4+0] = a.x + p.x;
      W[c*4+1] = a.y + p.y;
      W[c*4+2] = a.z + p.z;
      W[c*4+3] = a.w + p.w;
    }
  } else {
    float4 sv = *reinterpret_cast<const float4*>(st_b + ((size_t)bh*64+lane)*4);
    float4 pv = *reinterpret_cast<const float4*>(p_b  + ((size_t)hh*64+lane)*4);
    wb0 = sv.x+pv.x; wb1 = sv.y+pv.y; wb2 = sv.z+pv.z; wb3 = sv.w+pv.w;
  }

  const float* xbase = xs + (size_t)bh * (S_SEQ*D_DIM);
  float xcur = xbase[lane];                      // x_t[lane] for wave3

  for (int t=0; t<S_SEQ; ++t){
    const float* xr = xbase + t*D_DIM;           // uniform -> scalar loads
    float xnext = (t+1<S_SEQ)? xbase[(t+1)*D_DIM + lane] : 0.f;

    // ---- phase A: matvec with x (waves 0-2); beta partials (wave 3) ----
    float r = 0.f;
    if (wave < 3){
      float a0=0.f,a1=0.f,a2=0.f,a3=0.f;
      #pragma unroll
      for (int j=0;j<64;j+=4){
        a0 = fmaf(W[j+0], xr[j+0], a0);
        a1 = fmaf(W[j+1], xr[j+1], a1);
        a2 = fmaf(W[j+2], xr[j+2], a2);
        a3 = fmaf(W[j+3], xr[j+3], a3);
      }
      r = (a0+a1)+(a2+a3);
    }

    // ---- phase B ----
    if (wave == 0){
      y_out[((size_t)t*B_NUM + b)*HID_D + hh*D_DIM + lane] = r;   // y pre-update
    } else if (wave == 1 || wave == 2){
      float m = r;
      #pragma unroll
      for (int off=32; off; off>>=1) m = fmaxf(m, __shfl_xor(m,off));
      float e = __expf(r-m);
      float sum = e;
      #pragma unroll
      for (int off=32; off; off>>=1) sum += __shfl_xor(sum,off);
      float val = e/sum;
      if (wave==1) q_s[lane]=val; else k_s[lane]=val;
    } else {
      float p0 = wb0*xcur, p1 = wb1*xcur, p2 = wb2*xcur, p3 = wb3*xcur;
      #pragma unroll
      for (int off=32; off; off>>=1){
        p0 += __shfl_xor(p0,off); p1 += __shfl_xor(p1,off);
        p2 += __shfl_xor(p2,off); p3 += __shfl_xor(p3,off);
      }
      if (lane==0){
        beta_s[0] = 1.f/(1.f+__expf(-p0));
        beta_s[1] = 1.f/(1.f+__expf(-p1));
        beta_s[2] = 1.f/(1.f+__expf(-p2));
        beta_s[3] = 1.f/(1.f+__expf(-p3));
      }
    }
    __syncthreads();

    // ---- phase C: matvec with d=q-k; phase D: rank-1 update ----
    if (wave < 3){
      float a0=0.f,a1=0.f,a2=0.f,a3=0.f;
      #pragma unroll
      for (int j=0;j<64;j+=4){
        float4 qv = *reinterpret_cast<const float4*>(q_s+j);
        float4 kv = *reinterpret_cast<const float4*>(k_s+j);
        a0 = fmaf(W[j+0], qv.x-kv.x, a0);
        a1 = fmaf(W[j+1], qv.y-kv.y, a1);
        a2 = fmaf(W[j+2], qv.z-kv.z, a2);
        a3 = fmaf(W[j+3], qv.w-kv.w, a3);
      }
      float rd = (a0+a1)+(a2+a3);
      float cc = beta_s[wave] * rd;              // beta_w * dW[lane]
      #pragma unroll
      for (int j=0;j<64;j+=4){
        float4 kv = *reinterpret_cast<const float4*>(k_s+j);
        W[j+0] = fmaf(cc, kv.x, W[j+0]);
        W[j+1] = fmaf(cc, kv.y, W[j+1]);
        W[j+2] = fmaf(cc, kv.z, W[j+2]);
        W[j+3] = fmaf(cc, kv.w, W[j+3]);
      }
    } else {
      float dj = q_s[lane]-k_s[lane];
      float kj = k_s[lane];
      float d0 = wb0*dj, d1 = wb1*dj, d2 = wb2*dj, d3 = wb3*dj;
      #pragma unroll
      for (int off=32; off; off>>=1){
        d0 += __shfl_xor(d0,off); d1 += __shfl_xor(d1,off);
        d2 += __shfl_xor(d2,off); d3 += __shfl_xor(d3,off);
      }
      float bk = beta_s[3]*kj;                   // wb[j][c] += beta3*k[j]*db[c]
      wb0 = fmaf(bk, d0, wb0);
      wb1 = fmaf(bk, d1, wb1);
      wb2 = fmaf(bk, d2, wb2);
      wb3 = fmaf(bk, d3, wb3);
    }
    xcur = xnext;
    __syncthreads();
  }

  // ---- final states: (W_final - p) -> f32 outputs ----
  if (wave < 3){
    const float* pp = (wave==0)? p_y : (wave==1)? p_q : p_k;
    float* o = ((wave==0)? o_sy : (wave==1)? o_sq : o_sk) + ((size_t)bh*64 + lane)*64;
    const float4* p4 = reinterpret_cast<const float4*>(pp + ((size_t)hh*64 + lane)*64);
    #pragma unroll
    for (int c=0;c<16;c++){
      float4 p = p4[c];
      float4 w;
      w.x = W[c*4+0] - p.x;
      w.y = W[c*4+1] - p.y;
      w.z = W[c*4+2] - p.z;
      w.w = W[c*4+3] - p.w;
      reinterpret_cast<float4*>(o)[c] = w;
    }
  } else {
    float4 pv = *reinterpret_cast<const float4*>(p_b + ((size_t)hh*64+lane)*4);
    float4 w;
    w.x = wb0-pv.x; w.y = wb1-pv.y; w.z = wb2-pv.z; w.w = wb3-pv.w;
    *reinterpret_cast<float4*>(o_sb + ((size_t)bh*64+lane)*4) = w;
  }
}

// ---------------------------------------------------------------------------
// Vector f32 GEMM: C[m][n] = sum_k A[m][k]*B[n][k] (+bias)(+Cin)(relu)
// A: [M][K] f32 row-major, Bw: [N][K] f32 row-major.
// ---------------------------------------------------------------------------
template<int BM,int BN,int TM,int TN,bool BIAS,bool RELU,bool ADDC>
__global__ __launch_bounds__(256) void gemm_k(
    const float* __restrict__ A, const float* __restrict__ Bw,
    const float* __restrict__ Cin, const float* __restrict__ bias,
    float* __restrict__ Of,
    int M, int N, int K)
{
  constexpr int BK = 16;
  constexpr int TX = BN/TN;
  constexpr int TY = BM/TM;
  static_assert(TX*TY==256, "bad tiling");
  __shared__ __align__(16) float As[BK][BM];
  __shared__ __align__(16) float Bs[BK][BN];
  const int tid = threadIdx.x;
  const int tx = tid % TX;
  const int ty = tid / TX;
  const int m0 = blockIdx.y*BM, n0 = blockIdx.x*BN;
  float acc[TM][TN] = {};

  for (int k0=0; k0<K; k0+=BK){
    { // stage A (BM rows x BK cols, transposed into As[k][m])
      constexpr int E = BM*BK/256;       // elems per thread (8 or 4)
      constexpr int TPR = BK/E;          // threads per row
      int r  = tid / TPR;
      int kk = (tid % TPR) * E;
      const float* src = A + (size_t)(m0+r)*K + k0 + kk;
      #pragma unroll
      for (int c=0;c<E;c+=4){
        float4 v = *reinterpret_cast<const float4*>(src + c);
        As[kk+c+0][r]=v.x; As[kk+c+1][r]=v.y; As[kk+c+2][r]=v.z; As[kk+c+3][r]=v.w;
      }
    }
    { // stage B
      constexpr int E = BN*BK/256;
      constexpr int TPR = BK/E;
      int r  = tid / TPR;
      int kk = (tid % TPR) * E;
      const float* src = Bw + (size_t)(n0+r)*K + k0 + kk;
      #pragma unroll
      for (int c=0;c<E;c+=4){
        float4 v = *reinterpret_cast<const float4*>(src + c);
        Bs[kk+c+0][r]=v.x; Bs[kk+c+1][r]=v.y; Bs[kk+c+2][r]=v.z; Bs[kk+c+3][r]=v.w;
      }
    }
    __syncthreads();
    #pragma unroll
    for (int kk=0;kk<BK;kk++){
      float a[TM], bf[TN];
      #pragma unroll
      for (int i=0;i<TM;i++) a[i] = As[kk][ty*TM+i];
      #pragma unroll
      for (int j=0;j<TN;j++) bf[j] = Bs[kk][tx*TN+j];
      #pragma unroll
      for (int i=0;i<TM;i++)
        #pragma unroll
        for (int j=0;j<TN;j++)
          acc[i][j] = fmaf(a[i], bf[j], acc[i][j]);
    }
    __syncthreads();
  }

  #pragma unroll
  for (int i=0;i<TM;i++){
    int row = m0 + ty*TM + i;
    #pragma unroll
    for (int j0=0;j0<TN;j0+=4){
      int col = n0 + tx*TN + j0;
      float4 v = make_float4(acc[i][j0],acc[i][j0+1],acc[i][j0+2],acc[i][j0+3]);
      if (BIAS){
        float4 bv = *reinterpret_cast<const float4*>(bias+col);
        v.x += bv.x; v.y += bv.y; v.z += bv.z; v.w += bv.w;
      }
      if (ADDC){
        float4 c = *reinterpret_cast<const float4*>(Cin + (size_t)row*N + col);
        v.x+=c.x; v.y+=c.y; v.z+=c.z; v.w+=c.w;
      }
      if (RELU){
        v.x=fmaxf(v.x,0.f); v.y=fmaxf(v.y,0.f); v.z=fmaxf(v.z,0.f); v.w=fmaxf(v.w,0.f);
      }
      *reinterpret_cast<float4*>(Of + (size_t)row*N + col) = v;
    }
  }
}

// ---------------------------------------------------------------------------
// LayerNorm over HID=512, wave per row, 8 elems/lane. f32 -> f32.
// ---------------------------------------------------------------------------
__global__ __launch_bounds__(256) void ln_k(
    const float* __restrict__ h, const float* __restrict__ g,
    const float* __restrict__ bb, float* __restrict__ out)
{
  int row  = blockIdx.x*4 + (threadIdx.x>>6);
  int lane = threadIdx.x & 63;
  const float4* hr = reinterpret_cast<const float4*>(h + (size_t)row*HID_D) + lane*2;
  float4 u = hr[0], v = hr[1];
  float vals[8] = {u.x,u.y,u.z,u.w,v.x,v.y,v.z,v.w};
  float s = 0.f;
  #pragma unroll
  for (int e=0;e<8;e++) s += vals[e];
  #pragma unroll
  for (int off=32; off; off>>=1) s += __shfl_xor(s,off);
  float mu = s * (1.f/HID_D);
  float vs = 0.f;
  #pragma unroll
  for (int e=0;e<8;e++){ float d = vals[e]-mu; vs += d*d; }
  #pragma unroll
  for (int off=32; off; off>>=1) vs += __shfl_xor(vs,off);
  float rs = rsqrtf(vs*(1.f/HID_D) + 1e-5f);
  const float4* gr = reinterpret_cast<const float4*>(g) + lane*2;
  const float4* br = reinterpret_cast<const float4*>(bb) + lane*2;
  float4 g0 = gr[0], g1 = gr[1], b0 = br[0], b1 = br[1];
  float4 o0, o1;
  o0.x = (vals[0]-mu)*rs*g0.x + b0.x;
  o0.y = (vals[1]-mu)*rs*g0.y + b0.y;
  o0.z = (vals[2]-mu)*rs*g0.z + b0.z;
  o0.w = (vals[3]-mu)*rs*g0.w + b0.w;
  o1.x = (vals[4]-mu)*rs*g1.x + b1.x;
  o1.y = (vals[5]-mu)*rs*g1.y + b1.y;
  o1.z = (vals[6]-mu)*rs*g1.z + b1.z;
  o1.w = (vals[7]-mu)*rs*g1.w + b1.w;
  float4* orow = reinterpret_cast<float4*>(out + (size_t)row*HID_D) + lane*2;
  orow[0] = o0; orow[1] = o1;
}

// ---------------------------------------------------------------------------
extern "C" void kernel_launch(void* const* d_in, const int* in_sizes, int n_in,
                              void* d_out, int out_size, void* d_ws, size_t ws_size,
                              hipStream_t stream)
{
  const float* x    = (const float*)d_in[0];
  const float* sty  = (const float*)d_in[1];
  const float* stq  = (const float*)d_in[2];
  const float* stk  = (const float*)d_in[3];
  const float* stb  = (const float*)d_in[4];
  const float* inW  = (const float*)d_in[5];
  const float* inb  = (const float*)d_in[6];
  const float* py   = (const float*)d_in[7];
  const float* pq   = (const float*)d_in[8];
  const float* pk   = (const float*)d_in[9];
  const float* pb   = (const float*)d_in[10];
  const float* Wo   = (const float*)d_in[11];
  const float* fw1  = (const float*)d_in[12];
  const float* fb1  = (const float*)d_in[13];
  const float* fw2  = (const float*)d_in[14];
  const float* fb2  = (const float*)d_in[15];
  const float* lng  = (const float*)d_in[16];
  const float* lnb  = (const float*)d_in[17];

  char* ws = (char*)d_ws;
  float* h   = (float*)ws;                  // 4 MB (2048 x 512)
  float* xsb = (float*)(ws + (4<<20));      // 4 MB (B,H,S,D)
  float* yb  = (float*)(ws + (8<<20));      // 4 MB (S,B,HID)
  float* t0  = (float*)(ws + (12<<20));     // 4 MB (ln out)
  float* t1  = (float*)(ws + (16<<20));     // 16 MB (2048 x 2048)

  float* out0 = (float*)d_out;
  const size_t OUT_SZ = (size_t)S_SEQ*B_NUM*HID_D;          // 1048576
  const size_t SYL    = (size_t)B_NUM*H_NUM*D_DIM*D_DIM;    // 262144 per layer
  const size_t SBL    = (size_t)B_NUM*H_NUM*D_DIM*4;        // 16384  per layer
  float* o_sy = out0 + OUT_SZ;
  float* o_sq = o_sy + L_NUM*SYL;
  float* o_sk = o_sq + L_NUM*SYL;
  float* o_sb = o_sk + L_NUM*SYL;

  const int M = S_SEQ*B_NUM;   // 2048
  dim3 gN512(HID_D/64, M/128); // (8,16)

  // in-projection: h = x @ in_W.T + in_b
  gemm_k<128,64,8,4,true,false,false><<<gN512,256,0,stream>>>(
      x, inW, nullptr, inb, h, M, HID_D, 512);

  for (int l=0;l<L_NUM;l++){
    softmax_xs_k<<<(S_SEQ*B_NUM*H_NUM)/4, 256, 0, stream>>>(h, xsb);

    scan_k<<<B_NUM*H_NUM, 256, 0, stream>>>(xsb,
        sty + (size_t)l*SYL, stq + (size_t)l*SYL, stk + (size_t)l*SYL, stb + (size_t)l*SBL,
        py + (size_t)l*H_NUM*D_DIM*D_DIM, pq + (size_t)l*H_NUM*D_DIM*D_DIM,
        pk + (size_t)l*H_NUM*D_DIM*D_DIM, pb + (size_t)l*H_NUM*D_DIM*4,
        yb,
        o_sy + l*SYL, o_sq + l*SYL, o_sk + l*SYL, o_sb + l*SBL);

    // h += y @ Wo.T
    gemm_k<128,64,8,4,false,false,true><<<gN512,256,0,stream>>>(
        yb, Wo + (size_t)l*HID_D*HID_D, h, nullptr, h, M, HID_D, HID_D);

    ln_k<<<M/4,256,0,stream>>>(h, lng + l*HID_D, lnb + l*HID_D, t0);

    // t1 = relu(ln @ ff_W1.T + b1)
    gemm_k<128,128,8,8,true,true,false><<<dim3(FF_D/128, M/128),256,0,stream>>>(
        t0, fw1 + (size_t)l*FF_D*HID_D, nullptr, fb1 + l*FF_D, t1, M, FF_D, HID_D);

    // h(+out) = h + t1 @ ff_W2.T + b2   (last layer writes d_out directly)
    float* dst = (l==L_NUM-1) ? out0 : h;
    gemm_k<128,64,8,4,true,false,true><<<gN512,256,0,stream>>>(
        t1, fw2 + (size_t)l*HID_D*FF_D, h, fb2 + l*HID_D, dst, M, HID_D, FF_D);
  }
}